// Round 5
// baseline (489.178 us; speedup 1.0000x reference)
//
#include <hip/hip_runtime.h>
#include <math.h>

#define BG   128            // graphs
#define NPER 1024           // nodes per graph, level 0
#define HDIM 128            // hidden
#define NEDGE (BG * NPER * 8)
#define NMAX (BG * NPER)    // 131072
#define EPG  (NEDGE / BG)   // 8192 edges per graph (contiguous slice!)
#define CAP  48             // per-node edge capacity (Poisson(8) tail ~1e-15)
#define PRE  16             // packed-meta entries per node (P(deg>16) ~ 0.4%)
#define CROWS 64            // conv tile rows

typedef __attribute__((ext_vector_type(8))) short s16x8;   // 8 bf16 (4 VGPRs)
typedef __attribute__((ext_vector_type(4))) float f32x4;   // MFMA C/D

static __device__ __forceinline__ ushort f2bf(float f) {   // RNE f32 -> bf16
  uint u = __float_as_uint(f);
  return (ushort)((u + 0x7fffu + ((u >> 16) & 1u)) >> 16);
}
static __device__ __forceinline__ float bf2f(ushort h) {
  return __uint_as_float(((uint)h) << 16);
}

// ---------------------------------------------------------------------------
// L0 merged count+fill: ONE atomic per edge gives both the slot position and
// (at the end) the degree. meta holds ONLY graph-local src ids.
// ---------------------------------------------------------------------------

__global__ __launch_bounds__(256) void countfill_kernel(
    const int* __restrict__ cr, const int* __restrict__ cc,
    int* __restrict__ cnt, int* __restrict__ meta8,
    int* __restrict__ srcext, int mask) {
  int e = blockIdx.x * 256 + threadIdx.x;
  int c = cc[e];
  int rl = cr[e] & mask;                       // graph-local row index
  int pos = atomicAdd(&cnt[c], 1);
  if (pos < PRE) {
    meta8[(size_t)c * PRE + pos] = rl;
  } else if (pos < CAP) {
    srcext[(size_t)c * CAP + pos] = rl;
  }
}

// ---------------------------------------------------------------------------
// dinv table: one rsqrt per node per level (replaces per-edge rsqrt).
// ---------------------------------------------------------------------------

__global__ __launch_bounds__(256) void dinv_kernel(
    const int* __restrict__ cnt, float* __restrict__ dinv) {
  int i = blockIdx.x * 256 + threadIdx.x;
  dinv[i] = rsqrtf((float)cnt[i] + 1.0f);
}

// ---------------------------------------------------------------------------
// Aggregation R5: NO LDS staging (graph x-slab is 512 KB -> L2-resident;
// learn_hip lesson: don't LDS-stage what L2 fits). Group = 32 lanes owns a
// full 512 B row. Ids broadcast via shfl (lgkm); src rows + dinv gathered
// from GLOBAL (vmcnt) — different counters, chain no longer serializes.
// Fixed-16 masked trip for straight-line ILP; masked-out slots load the
// dst's own row (L1-hit) so no L2 bandwidth is wasted. Zero LDS -> up to
// 32 waves/CU. Node-sliced grid (graph x 8): meta/cnt/dinv read once per
// node (channel-split would duplicate them — R2's regression).
// ---------------------------------------------------------------------------

__global__ __launch_bounds__(512, 8) void agg_gather_kernel(
    const float* __restrict__ x, float* __restrict__ z,
    const int* __restrict__ meta8, const int* __restrict__ srcext,
    const int* __restrict__ cnt, const float* __restrict__ dinv, int npg) {
  int b = blockIdx.x;
  int g = b >> 3, q = b & 7;                   // graph, node-slice
  int t = threadIdx.x;
  int li = t & 31, gi = t >> 5;                // lane-in-group, group 0..15
  int base = g * npg;
  int nmask = npg - 1;
  int qbase = q * (npg >> 3);
  int sl_base = t & 32;                        // shfl source half of wave

  const float4* x4 = (const float4*)x;
  const int2* m2 = (const int2*)meta8;
  const float* dvt = dinv + base;
  float4* z4 = (float4*)z;

  int passes = npg >> 7;                       // (npg/8 dsts) / 16 groups
  for (int p = 0; p < passes; ++p) {
    int dst = qbase + p * 16 + gi;
    int node = base + dst;
    int2 mq = m2[(size_t)node * 8 + (li & 7)]; // 16 ids in lanes 0..7 of half
    int dg = cnt[node];
    float dvc = dvt[dst];
    int d = dg > CAP ? CAP : dg;
    int dp = d > PRE ? PRE : d;

    float4 vs = x4[(size_t)node * 32 + li];    // self row slice
    float4 a0, a1;
    a0.x = vs.x * dvc; a0.y = vs.y * dvc;
    a0.z = vs.z * dvc; a0.w = vs.w * dvc;
    a1 = make_float4(0.f, 0.f, 0.f, 0.f);

    #pragma unroll
    for (int e = 0; e < PRE; e += 2) {         // fixed trip, branch-free
      int sl = sl_base + (e >> 1);
      int r0 = __shfl(mq.x, sl) & nmask;
      int r1 = __shfl(mq.y, sl) & nmask;
      int s0 = (e < dp) ? r0 : dst;            // invalid -> own row (L1 hit)
      int s1 = (e + 1 < dp) ? r1 : dst;
      float4 v0 = x4[(size_t)(base + s0) * 32 + li];
      float4 v1 = x4[(size_t)(base + s1) * 32 + li];
      float dv0 = dvt[s0];
      float dv1 = dvt[s1];
      dv0 = (e < dp) ? dv0 : 0.f;              // mask folded into coefficient
      dv1 = (e + 1 < dp) ? dv1 : 0.f;
      a0.x = fmaf(dv0, v0.x, a0.x); a0.y = fmaf(dv0, v0.y, a0.y);
      a0.z = fmaf(dv0, v0.z, a0.z); a0.w = fmaf(dv0, v0.w, a0.w);
      a1.x = fmaf(dv1, v1.x, a1.x); a1.y = fmaf(dv1, v1.y, a1.y);
      a1.z = fmaf(dv1, v1.z, a1.z); a1.w = fmaf(dv1, v1.w, a1.w);
    }

    if (d > PRE) {                             // rare overflow (deg > 16)
      for (int e2 = PRE; e2 < d; ++e2) {
        int rl = srcext[(size_t)node * CAP + e2];
        float dv0 = dvt[rl];
        float4 v0 = x4[(size_t)(base + rl) * 32 + li];
        a0.x = fmaf(dv0, v0.x, a0.x); a0.y = fmaf(dv0, v0.y, a0.y);
        a0.z = fmaf(dv0, v0.z, a0.z); a0.w = fmaf(dv0, v0.w, a0.w);
      }
    }

    float4 o = make_float4((a0.x + a1.x) * dvc, (a0.y + a1.y) * dvc,
                           (a0.z + a1.z) * dvc, (a0.w + a1.w) * dvc);
    z4[(size_t)node * 32 + li] = o;
  }
}

// ---------------------------------------------------------------------------
// W prep: 3-way bf16 split (hi/mid/lo, residual <= 2^-27 rel) of each level's
// W, packed directly in MFMA B-fragment order for 16x16x32_bf16:
//   B[k][n]: lane l holds k = kt*32 + (l>>4)*8 + i, n = nt*16 + (l&15)
//   layout: [L][split][kt][nt][lane][i]  (each fragment = 16 B contiguous)
// Runs once; 3*3*32 KB total.
// ---------------------------------------------------------------------------

__global__ __launch_bounds__(256) void wsplit_kernel(
    const float* __restrict__ W0, const float* __restrict__ W1,
    const float* __restrict__ W2, ushort* __restrict__ wpk) {
  int id = blockIdx.x * 256 + threadIdx.x;     // 3*16384 total
  int L = id >> 14;
  int r = id & 16383;                          // ((kt*8+nt)*64+lane)*8+i
  int i = r & 7;
  int lane = (r >> 3) & 63;
  int nt = (r >> 9) & 7;
  int kt = (r >> 12) & 3;
  int k = kt * 32 + (lane >> 4) * 8 + i;
  int n = nt * 16 + (lane & 15);
  const float* W = (L == 0) ? W0 : (L == 1) ? W1 : W2;
  float v = W[k * HDIM + n];
  ushort h = f2bf(v);
  float r1 = v - bf2f(h);
  ushort m = f2bf(r1);
  ushort lo = f2bf(r1 - bf2f(m));
  size_t base = (size_t)L * 3 * 16384 + (size_t)r;
  wpk[base] = h;
  wpk[base + 16384] = m;
  wpk[base + 32768] = lo;
}

// ---------------------------------------------------------------------------
// conv via MFMA split-precision: h = relu(z @ W + b) in-place; score = h . p.
// Each wave owns 16 rows (4 waves = 64 rows/block). fp32 z is 3-way bf16
// split in registers; 6 product terms (hh,hm,mh,hl,lh,mm) per K-tile keep
// error ~2^-27 rel (fp32-rounding level -> topk ordering preserved).
// B-fragments: coalesced 16 B/lane dwordx4 from pre-packed wpk (L2-hot).
// No LDS, no barriers. 192 MFMAs/wave; dispatch is memory-bound on z/h.
// ---------------------------------------------------------------------------

__global__ __launch_bounds__(256) void conv_mfma_kernel(
    float* __restrict__ zh, const ushort* __restrict__ wpk,
    const float* __restrict__ bias, const float* __restrict__ p,
    float* __restrict__ score) {
  int t = threadIdx.x;
  int wv = t >> 6, l = t & 63;
  int lr = l & 15, lq = l >> 4;                // A-row in tile, quarter
  int arow = blockIdx.x * CROWS + wv * 16 + lr;
  const float* zrow = zh + (size_t)arow * HDIM + lq * 8;

  // ---- load + 3-way split A fragments (k = kt*32 + lq*8 + i) ----
  s16x8 ah[4], am[4], al[4];
  #pragma unroll
  for (int kt = 0; kt < 4; ++kt) {
    float4 v0 = ((const float4*)(zrow + kt * 32))[0];
    float4 v1 = ((const float4*)(zrow + kt * 32))[1];
    float f[8] = {v0.x, v0.y, v0.z, v0.w, v1.x, v1.y, v1.z, v1.w};
    #pragma unroll
    for (int i = 0; i < 8; ++i) {
      ushort h = f2bf(f[i]);
      float r1 = f[i] - bf2f(h);
      ushort m = f2bf(r1);
      ushort lo = f2bf(r1 - bf2f(m));
      ah[kt][i] = (short)h; am[kt][i] = (short)m; al[kt][i] = (short)lo;
    }
  }

  f32x4 acc[8];
  #pragma unroll
  for (int nt = 0; nt < 8; ++nt) acc[nt] = (f32x4)(0.f);

  const s16x8* wh = (const s16x8*)wpk;         // fragment-granular views
  const s16x8* wm = wh + 2048;
  const s16x8* wl = wm + 2048;

  #pragma unroll
  for (int kt = 0; kt < 4; ++kt) {
    #pragma unroll
    for (int nt = 0; nt < 8; ++nt) {
      int fi = (kt * 8 + nt) * 64 + l;
      s16x8 bh = wh[fi];
      s16x8 bm = wm[fi];
      s16x8 bl = wl[fi];
      acc[nt] = __builtin_amdgcn_mfma_f32_16x16x32_bf16(ah[kt], bh, acc[nt], 0, 0, 0);
      acc[nt] = __builtin_amdgcn_mfma_f32_16x16x32_bf16(ah[kt], bm, acc[nt], 0, 0, 0);
      acc[nt] = __builtin_amdgcn_mfma_f32_16x16x32_bf16(am[kt], bh, acc[nt], 0, 0, 0);
      acc[nt] = __builtin_amdgcn_mfma_f32_16x16x32_bf16(ah[kt], bl, acc[nt], 0, 0, 0);
      acc[nt] = __builtin_amdgcn_mfma_f32_16x16x32_bf16(al[kt], bh, acc[nt], 0, 0, 0);
      acc[nt] = __builtin_amdgcn_mfma_f32_16x16x32_bf16(am[kt], bm, acc[nt], 0, 0, 0);
    }
  }

  // ---- epilogue: bias + relu + score + in-place store ----
  // C/D layout (m89-verified): row = lq*4 + j, col = nt*16 + lr
  int orow = blockIdx.x * CROWS + wv * 16 + lq * 4;
  float part[4] = {0.f, 0.f, 0.f, 0.f};
  #pragma unroll
  for (int nt = 0; nt < 8; ++nt) {
    float bv = bias[nt * 16 + lr];
    float pv = p[nt * 16 + lr];
    #pragma unroll
    for (int j = 0; j < 4; ++j) {
      float hv = fmaxf(acc[nt][j] + bv, 0.f);
      part[j] += hv * pv;
      zh[(size_t)(orow + j) * HDIM + nt * 16 + lr] = hv;
    }
  }
  #pragma unroll
  for (int j = 0; j < 4; ++j) {
    #pragma unroll
    for (int s = 1; s < 16; s <<= 1) part[j] += __shfl_xor(part[j], s);
    if (lr == 0) score[orow + j] = part[j];
  }
}

// ---------------------------------------------------------------------------
// MEGA: per-graph block (P threads) — sort + pool/readout + relabel + next-
// layer count/fill via LDS. Coefficient-free meta: relabel loop writes meta8
// directly with ONE LDS atomic (slot+count combined); no second fill pass,
// no barrier between count and fill. L==2 also emits the final output.
// ---------------------------------------------------------------------------

__global__ __launch_bounds__(1024) void topk_mega_kernel(
    const float* __restrict__ score, const float* __restrict__ p,
    const float* __restrict__ h, float* __restrict__ xo,
    const int* __restrict__ in_r, const int* __restrict__ in_c,
    int* __restrict__ out_r, int* __restrict__ out_c,
    int* __restrict__ meta8, int* __restrict__ srcext,
    int* __restrict__ cnt, float* __restrict__ acc,
    float* __restrict__ outf, int P, int K, int L) {
  __shared__ float sv[1024];
  __shared__ int si[1024];
  __shared__ int snew[1024];
  __shared__ int scnt[512];
  __shared__ float s_pn;
  __shared__ float4 smx[32][32], ssm[32][32];
  int g = blockIdx.x;
  int t = threadIdx.x;

  if (L < 2 && t < 512) scnt[t] = 0;
  snew[t] = -1;
  if (t < 128) { float v = p[t]; sv[t] = v * v; }
  __syncthreads();
  for (int off = 64; off; off >>= 1) {
    if (t < off) sv[t] += sv[t + off];
    __syncthreads();
  }
  if (t == 0) s_pn = sqrtf(sv[0]);
  __syncthreads();
  float pn = s_pn;

  sv[t] = score[(size_t)g * P + t];
  si[t] = t;
  for (int size = 2; size <= P; size <<= 1) {
    for (int stride = size >> 1; stride; stride >>= 1) {
      __syncthreads();
      int j = t ^ stride;
      if (j > t) {
        float a = sv[t], b = sv[j];
        int ia = si[t], ib = si[j];
        bool tFirst = (a > b) || (a == b && ia < ib);
        bool up = ((t & size) == 0);
        if (up ? !tFirst : tFirst) {
          sv[t] = b; sv[j] = a;
          si[t] = ib; si[j] = ia;
        }
      }
    }
  }
  __syncthreads();
  if (t < K) {
    snew[si[t]] = t;                           // graph-LOCAL new id
    sv[t] = tanhf(sv[t] / pn);                 // sv now holds the scale
  }
  __syncthreads();

  // ---- gather + readout: group = 32 lanes, 16 rows per group ----
  int lane = t & 31, grp = t >> 5;             // ngrp = P/32; K/ngrp == 16
  const float4* h4 = (const float4*)h;
  float4* xo4 = (float4*)xo;
  size_t hbase = (size_t)g * P * 32;
  float4 mx = make_float4(-INFINITY, -INFINITY, -INFINITY, -INFINITY);
  float4 sm = make_float4(0.f, 0.f, 0.f, 0.f);
  #pragma unroll
  for (int i = 0; i < 16; ++i) {
    int j = grp * 16 + i;
    float th = sv[j];
    float4 v = h4[hbase + (size_t)si[j] * 32 + lane];
    v.x *= th; v.y *= th; v.z *= th; v.w *= th;
    xo4[((size_t)g * K + j) * 32 + lane] = v;
    mx.x = fmaxf(mx.x, v.x); mx.y = fmaxf(mx.y, v.y);
    mx.z = fmaxf(mx.z, v.z); mx.w = fmaxf(mx.w, v.w);
    sm.x += v.x; sm.y += v.y; sm.z += v.z; sm.w += v.w;
  }
  smx[grp][lane] = mx;
  ssm[grp][lane] = sm;
  __syncthreads();
  int ngrp = P >> 5;
  if (grp == 0) {
    for (int s2 = 1; s2 < ngrp; ++s2) {
      float4 m2 = smx[s2][lane], s3 = ssm[s2][lane];
      mx.x = fmaxf(mx.x, m2.x); mx.y = fmaxf(mx.y, m2.y);
      mx.z = fmaxf(mx.z, m2.z); mx.w = fmaxf(mx.w, m2.w);
      sm.x += s3.x; sm.y += s3.y; sm.z += s3.z; sm.w += s3.w;
    }
    int c0 = lane * 4;
    if (L < 2) {
      float* amax = acc + (size_t)L * BG * 256 + (size_t)g * 256;
      float* asum = amax + 128;
      amax[c0 + 0] = mx.x; amax[c0 + 1] = mx.y;
      amax[c0 + 2] = mx.z; amax[c0 + 3] = mx.w;
      asum[c0 + 0] = sm.x; asum[c0 + 1] = sm.y;
      asum[c0 + 2] = sm.z; asum[c0 + 3] = sm.w;
    } else {                                   // stash own readout in sv
      sv[c0 + 0] = mx.x; sv[c0 + 1] = mx.y;
      sv[c0 + 2] = mx.z; sv[c0 + 3] = mx.w;
      sv[128 + c0 + 0] = sm.x; sv[128 + c0 + 1] = sm.y;
      sv[128 + c0 + 2] = sm.z; sv[128 + c0 + 3] = sm.w;
    }
  }

  if (L == 2) {                                // fold final combine in
    __syncthreads();
    float v;
    const float* a0 = acc + (size_t)g * 256;
    const float* a1 = acc + (size_t)BG * 256 + (size_t)g * 256;
    if (t < 128) {
      v = a0[t] + a1[t] + sv[t];
    } else {
      v = a0[t] * (1.f / 512.f) + a1[t] * (1.f / 256.f) + sv[t] * (1.f / 128.f);
    }
    outf[g * 256 + t] = v;
    return;
  }

  // ---- relabel + count + fill in ONE pass (single LDS atomic per edge) ----
  int ept = EPG / P;                           // 8 (P=1024) or 16 (P=512)
  int ebase = g * EPG;
  for (int i = 0; i < ept; ++i) {
    int e = ebase + i * P + t;                 // coalesced
    int r = in_r[e];
    int nr = -1, nc = -1;
    if (r >= 0) {
      nr = snew[r & (P - 1)];
      nc = snew[in_c[e] & (P - 1)];
    }
    bool ok = (nr >= 0) && (nc >= 0);
    out_r[e] = ok ? g * K + nr : -1;
    out_c[e] = ok ? g * K + nc : -1;
    if (ok) {
      int pos = atomicAdd(&scnt[nc], 1);
      size_t gnode = (size_t)g * K + nc;
      if (pos < PRE) {
        meta8[gnode * PRE + pos] = nr;
      } else if (pos < CAP) {
        srcext[gnode * CAP + pos] = nr;
      }
    }
  }
  __syncthreads();                             // scnt complete
  if (t < K) cnt[g * K + t] = scnt[t];         // deg for next agg (coalesced)
}

// ---------------------------------------------------------------------------
// launch
// ---------------------------------------------------------------------------

extern "C" void kernel_launch(void* const* d_in, const int* in_sizes, int n_in,
                              void* d_out, int out_size, void* d_ws, size_t ws_size,
                              hipStream_t stream) {
  const float* x0 = (const float*)d_in[0];
  const int* erow = (const int*)d_in[1];
  const int* ecol = (const int*)d_in[2];
  const float* Wm[3] = {(const float*)d_in[3], (const float*)d_in[6], (const float*)d_in[9]};
  const float* bm[3] = {(const float*)d_in[4], (const float*)d_in[7], (const float*)d_in[10]};
  const float* pm[3] = {(const float*)d_in[5], (const float*)d_in[8], (const float*)d_in[11]};

  char* w = (char*)d_ws;
  size_t off = 0;
  auto alloc = [&](size_t bytes) -> void* {
    void* ptr = w + off;
    off = (off + bytes + 255) & ~(size_t)255;
    return ptr;
  };
  int* cur_row = (int*)alloc((size_t)NEDGE * 4);
  int* cur_col = (int*)alloc((size_t)NEDGE * 4);
  int* meta8   = (int*)alloc((size_t)NMAX * PRE * 4);
  int* srcext  = (int*)alloc((size_t)NMAX * CAP * 4);
  int* cnt     = (int*)alloc((size_t)NMAX * 4);
  float* dinv  = (float*)alloc((size_t)NMAX * 4);
  float* score = (float*)alloc((size_t)NMAX * 4);
  float* acc   = (float*)alloc((size_t)2 * BG * 256 * 4);
  float* zh    = (float*)alloc((size_t)NMAX * HDIM * 4);
  float* x1    = (float*)alloc((size_t)BG * 512 * HDIM * 4);
  float* x2    = (float*)alloc((size_t)BG * 256 * HDIM * 4);
  float* x3    = (float*)alloc((size_t)BG * 128 * HDIM * 4);
  ushort* wpk  = (ushort*)alloc((size_t)3 * 3 * 16384 * 2);  // packed W splits

  hipMemsetAsync(cnt, 0, (size_t)NMAX * 4, stream);
  countfill_kernel<<<NEDGE / 256, 256, 0, stream>>>(erow, ecol, cnt, meta8,
                                                    srcext, NPER - 1);
  wsplit_kernel<<<(3 * 16384) / 256, 256, 0, stream>>>(Wm[0], Wm[1], Wm[2], wpk);

  const float* xin = x0;
  float* xout[3] = {x1, x2, x3};
  int Ps[3] = {1024, 512, 256};

  for (int L = 0; L < 3; ++L) {
    int P = Ps[L];
    int K = P >> 1;
    int n = BG * P;
    const int* in_r = (L == 0) ? erow : cur_row;
    const int* in_c = (L == 0) ? ecol : cur_col;

    dinv_kernel<<<n / 256, 256, 0, stream>>>(cnt, dinv);
    agg_gather_kernel<<<BG * 8, 512, 0, stream>>>(
        xin, zh, meta8, srcext, cnt, dinv, P);
    conv_mfma_kernel<<<n / CROWS, 256, 0, stream>>>(
        zh, wpk + (size_t)L * 3 * 16384, bm[L], pm[L], score);
    topk_mega_kernel<<<BG, P, 0, stream>>>(
        score, pm[L], zh, xout[L], in_r, in_c, cur_row, cur_col,
        meta8, srcext, cnt, acc, (float*)d_out, P, K, L);
    xin = xout[L];
  }
}

// Round 6
// 381.996 us; speedup vs baseline: 1.2806x; 1.2806x over previous
//
#include <hip/hip_runtime.h>
#include <math.h>

#define BG   128            // graphs
#define NPER 1024           // nodes per graph, level 0
#define HDIM 128            // hidden
#define NEDGE (BG * NPER * 8)
#define NMAX (BG * NPER)    // 131072
#define EPG  (NEDGE / BG)   // 8192 edges per graph (contiguous slice!)
#define CAP  48             // per-node edge capacity (Poisson(8) tail ~1e-15)
#define PRE  16             // packed-meta entries per node (P(deg>16) ~ 0.4%)
#define CROWS 64            // conv tile rows

typedef __attribute__((ext_vector_type(8))) short s16x8;   // 8 bf16 (4 VGPRs)
typedef __attribute__((ext_vector_type(4))) float f32x4;   // MFMA C/D

static __device__ __forceinline__ ushort f2bf(float f) {   // RNE f32 -> bf16
  uint u = __float_as_uint(f);
  return (ushort)((u + 0x7fffu + ((u >> 16) & 1u)) >> 16);
}
static __device__ __forceinline__ float bf2f(ushort h) {
  return __uint_as_float(((uint)h) << 16);
}

// ---------------------------------------------------------------------------
// L0 merged count+fill: ONE atomic per edge gives both the slot position and
// (at the end) the degree. meta holds ONLY graph-local src ids.
// ---------------------------------------------------------------------------

__global__ __launch_bounds__(256) void countfill_kernel(
    const int* __restrict__ cr, const int* __restrict__ cc,
    int* __restrict__ cnt, int* __restrict__ meta8,
    int* __restrict__ srcext, int mask) {
  int e = blockIdx.x * 256 + threadIdx.x;
  int c = cc[e];
  int rl = cr[e] & mask;                       // graph-local row index
  int pos = atomicAdd(&cnt[c], 1);
  if (pos < PRE) {
    meta8[(size_t)c * PRE + pos] = rl;
  } else if (pos < CAP) {
    srcext[(size_t)c * CAP + pos] = rl;
  }
}

extern __shared__ float ldsbuf[];

// ---------------------------------------------------------------------------
// LDS-resident aggregation R6 = R1 + ONE change: id distribution.
// R1's serializer was __shfl (ds_bpermute) + dependent ds_read on the same
// in-order lgkm counter (2 round-trips per edge pair). Now each lane loads
// its node's 16 src ids as 4x int4 GLOBAL loads (group-uniform address ->
// one L1 fetch, broadcast; R4 measured FETCH stays ~50 MB with this).
// Ids sit in VGPRs from loop top (vmcnt); the lgkm chain is pure
// ds_read->fma with addresses known: 4 batches x 4 independent
// ds_read_b128, one lgkm wait per batch, 4 independent accumulators.
// Everything else identical to R1 (4x32-ch chunks, 132 KB LDS, grid BG*4).
// ---------------------------------------------------------------------------

static __device__ __forceinline__ void edge4(
    const float4* sX4, int4 iv, int eb, int dp, int dst, int nmask, int l,
    float4& a0, float4& a1, float4& a2, float4& a3) {
  int s0 = (eb + 0 < dp) ? (iv.x & nmask) : dst;   // invalid -> own row
  int s1 = (eb + 1 < dp) ? (iv.y & nmask) : dst;
  int s2 = (eb + 2 < dp) ? (iv.z & nmask) : dst;
  int s3 = (eb + 3 < dp) ? (iv.w & nmask) : dst;
  float m0 = (eb + 0 < dp) ? 1.f : 0.f;
  float m1 = (eb + 1 < dp) ? 1.f : 0.f;
  float m2 = (eb + 2 < dp) ? 1.f : 0.f;
  float m3 = (eb + 3 < dp) ? 1.f : 0.f;
  float4 v0 = sX4[s0 * 8 + l];                 // 4 independent ds_read_b128
  float4 v1 = sX4[s1 * 8 + l];
  float4 v2 = sX4[s2 * 8 + l];
  float4 v3 = sX4[s3 * 8 + l];
  a0.x = fmaf(m0, v0.x, a0.x); a0.y = fmaf(m0, v0.y, a0.y);
  a0.z = fmaf(m0, v0.z, a0.z); a0.w = fmaf(m0, v0.w, a0.w);
  a1.x = fmaf(m1, v1.x, a1.x); a1.y = fmaf(m1, v1.y, a1.y);
  a1.z = fmaf(m1, v1.z, a1.z); a1.w = fmaf(m1, v1.w, a1.w);
  a2.x = fmaf(m2, v2.x, a2.x); a2.y = fmaf(m2, v2.y, a2.y);
  a2.z = fmaf(m2, v2.z, a2.z); a2.w = fmaf(m2, v2.w, a2.w);
  a3.x = fmaf(m3, v3.x, a3.x); a3.y = fmaf(m3, v3.y, a3.y);
  a3.z = fmaf(m3, v3.z, a3.z); a3.w = fmaf(m3, v3.w, a3.w);
}

__global__ __launch_bounds__(1024) void agg_lds_kernel(
    const float* __restrict__ x, float* __restrict__ z,
    const int* __restrict__ meta8, const int* __restrict__ srcext,
    const int* __restrict__ deg, int npg) {
  float* sX = ldsbuf;                          // [npg][32], pre-scaled
  float* sDinv = sX + npg * 32;                // [npg]
  int g = blockIdx.x >> 2;
  int chunk = blockIdx.x & 3;
  int t = threadIdx.x;
  int base = g * npg;
  int nmask = npg - 1;

  const float4* x4 = (const float4*)x;
  float4* sX4 = (float4*)sX;
  for (int i = t; i < npg * 8; i += 1024) {
    int r = i >> 3, l8 = i & 7;
    float dv = rsqrtf((float)deg[base + r] + 1.0f);
    float4 v = x4[(size_t)(base + r) * 32 + chunk * 8 + l8];
    v.x *= dv; v.y *= dv; v.z *= dv; v.w *= dv;
    sX4[i] = v;
  }
  for (int i = t; i < npg; i += 1024)
    sDinv[i] = rsqrtf((float)deg[base + i] + 1.0f);
  __syncthreads();

  int dl = t >> 3, l = t & 7;                  // dst-local slot, lane 0..7
  const int4* m4 = (const int4*)meta8;
  float4* z4 = (float4*)z;

  for (int dst = dl; dst < npg; dst += 128) {
    int node = base + dst;
    int4 i0 = m4[(size_t)node * 4 + 0];        // 16 ids, group-uniform addr
    int4 i1 = m4[(size_t)node * 4 + 1];        // (L1 broadcast), vmcnt
    int4 i2 = m4[(size_t)node * 4 + 2];
    int4 i3 = m4[(size_t)node * 4 + 3];
    int dg = deg[node];
    int d = dg > CAP ? CAP : dg;
    int dp = d > PRE ? PRE : d;
    float dc = sDinv[dst];
    float4 a0 = sX4[dst * 8 + l];              // self term (xs[c]); *dc later
    float4 a1 = make_float4(0.f, 0.f, 0.f, 0.f);
    float4 a2 = make_float4(0.f, 0.f, 0.f, 0.f);
    float4 a3 = make_float4(0.f, 0.f, 0.f, 0.f);

    edge4(sX4, i0, 0, dp, dst, nmask, l, a0, a1, a2, a3);
    edge4(sX4, i1, 4, dp, dst, nmask, l, a0, a1, a2, a3);
    edge4(sX4, i2, 8, dp, dst, nmask, l, a0, a1, a2, a3);
    edge4(sX4, i3, 12, dp, dst, nmask, l, a0, a1, a2, a3);

    if (d > PRE) {                             // rare overflow (deg > 16)
      for (int e2 = PRE; e2 < d; ++e2) {
        int rl = srcext[(size_t)node * CAP + e2];
        float4 v0 = sX4[rl * 8 + l];
        a0.x += v0.x; a0.y += v0.y; a0.z += v0.z; a0.w += v0.w;
      }
    }
    float4 o = make_float4((a0.x + a1.x + a2.x + a3.x) * dc,
                           (a0.y + a1.y + a2.y + a3.y) * dc,
                           (a0.z + a1.z + a2.z + a3.z) * dc,
                           (a0.w + a1.w + a2.w + a3.w) * dc);
    z4[(size_t)node * 32 + chunk * 8 + l] = o;
  }
}

// ---------------------------------------------------------------------------
// W prep: 3-way bf16 split (hi/mid/lo, residual <= 2^-27 rel) of each level's
// W, packed directly in MFMA B-fragment order for 16x16x32_bf16:
//   B[k][n]: lane l holds k = kt*32 + (l>>4)*8 + i, n = nt*16 + (l&15)
//   layout: [L][split][kt][nt][lane][i]  (each fragment = 16 B contiguous)
// Runs once; 3*3*32 KB total.
// ---------------------------------------------------------------------------

__global__ __launch_bounds__(256) void wsplit_kernel(
    const float* __restrict__ W0, const float* __restrict__ W1,
    const float* __restrict__ W2, ushort* __restrict__ wpk) {
  int id = blockIdx.x * 256 + threadIdx.x;     // 3*16384 total
  int L = id >> 14;
  int r = id & 16383;                          // ((kt*8+nt)*64+lane)*8+i
  int i = r & 7;
  int lane = (r >> 3) & 63;
  int nt = (r >> 9) & 7;
  int kt = (r >> 12) & 3;
  int k = kt * 32 + (lane >> 4) * 8 + i;
  int n = nt * 16 + (lane & 15);
  const float* W = (L == 0) ? W0 : (L == 1) ? W1 : W2;
  float v = W[k * HDIM + n];
  ushort h = f2bf(v);
  float r1 = v - bf2f(h);
  ushort m = f2bf(r1);
  ushort lo = f2bf(r1 - bf2f(m));
  size_t base = (size_t)L * 3 * 16384 + (size_t)r;
  wpk[base] = h;
  wpk[base + 16384] = m;
  wpk[base + 32768] = lo;
}

// ---------------------------------------------------------------------------
// conv via MFMA split-precision: h = relu(z @ W + b) in-place; score = h . p.
// Each wave owns 16 rows (4 waves = 64 rows/block). fp32 z is 3-way bf16
// split in registers; 6 product terms (hh,hm,mh,hl,lh,mm) per K-tile keep
// error ~2^-27 rel (fp32-rounding level -> topk ordering preserved).
// B-fragments: coalesced 16 B/lane dwordx4 from pre-packed wpk (L2-hot).
// No LDS, no barriers. 192 MFMAs/wave; dispatch is memory-bound on z/h.
// ---------------------------------------------------------------------------

__global__ __launch_bounds__(256) void conv_mfma_kernel(
    float* __restrict__ zh, const ushort* __restrict__ wpk,
    const float* __restrict__ bias, const float* __restrict__ p,
    float* __restrict__ score) {
  int t = threadIdx.x;
  int wv = t >> 6, l = t & 63;
  int lr = l & 15, lq = l >> 4;                // A-row in tile, quarter
  int arow = blockIdx.x * CROWS + wv * 16 + lr;
  const float* zrow = zh + (size_t)arow * HDIM + lq * 8;

  // ---- load + 3-way split A fragments (k = kt*32 + lq*8 + i) ----
  s16x8 ah[4], am[4], al[4];
  #pragma unroll
  for (int kt = 0; kt < 4; ++kt) {
    float4 v0 = ((const float4*)(zrow + kt * 32))[0];
    float4 v1 = ((const float4*)(zrow + kt * 32))[1];
    float f[8] = {v0.x, v0.y, v0.z, v0.w, v1.x, v1.y, v1.z, v1.w};
    #pragma unroll
    for (int i = 0; i < 8; ++i) {
      ushort h = f2bf(f[i]);
      float r1 = f[i] - bf2f(h);
      ushort m = f2bf(r1);
      ushort lo = f2bf(r1 - bf2f(m));
      ah[kt][i] = (short)h; am[kt][i] = (short)m; al[kt][i] = (short)lo;
    }
  }

  f32x4 acc[8];
  #pragma unroll
  for (int nt = 0; nt < 8; ++nt) acc[nt] = (f32x4)(0.f);

  const s16x8* wh = (const s16x8*)wpk;         // fragment-granular views
  const s16x8* wm = wh + 2048;
  const s16x8* wl = wm + 2048;

  #pragma unroll
  for (int kt = 0; kt < 4; ++kt) {
    #pragma unroll
    for (int nt = 0; nt < 8; ++nt) {
      int fi = (kt * 8 + nt) * 64 + l;
      s16x8 bh = wh[fi];
      s16x8 bm = wm[fi];
      s16x8 bl = wl[fi];
      acc[nt] = __builtin_amdgcn_mfma_f32_16x16x32_bf16(ah[kt], bh, acc[nt], 0, 0, 0);
      acc[nt] = __builtin_amdgcn_mfma_f32_16x16x32_bf16(ah[kt], bm, acc[nt], 0, 0, 0);
      acc[nt] = __builtin_amdgcn_mfma_f32_16x16x32_bf16(am[kt], bh, acc[nt], 0, 0, 0);
      acc[nt] = __builtin_amdgcn_mfma_f32_16x16x32_bf16(ah[kt], bl, acc[nt], 0, 0, 0);
      acc[nt] = __builtin_amdgcn_mfma_f32_16x16x32_bf16(al[kt], bh, acc[nt], 0, 0, 0);
      acc[nt] = __builtin_amdgcn_mfma_f32_16x16x32_bf16(am[kt], bm, acc[nt], 0, 0, 0);
    }
  }

  // ---- epilogue: bias + relu + score + in-place store ----
  // C/D layout (m89-verified): row = lq*4 + j, col = nt*16 + lr
  int orow = blockIdx.x * CROWS + wv * 16 + lq * 4;
  float part[4] = {0.f, 0.f, 0.f, 0.f};
  #pragma unroll
  for (int nt = 0; nt < 8; ++nt) {
    float bv = bias[nt * 16 + lr];
    float pv = p[nt * 16 + lr];
    #pragma unroll
    for (int j = 0; j < 4; ++j) {
      float hv = fmaxf(acc[nt][j] + bv, 0.f);
      part[j] += hv * pv;
      zh[(size_t)(orow + j) * HDIM + nt * 16 + lr] = hv;
    }
  }
  #pragma unroll
  for (int j = 0; j < 4; ++j) {
    #pragma unroll
    for (int s = 1; s < 16; s <<= 1) part[j] += __shfl_xor(part[j], s);
    if (lr == 0) score[orow + j] = part[j];
  }
}

// ---------------------------------------------------------------------------
// MEGA: per-graph block (P threads) — sort + pool/readout + relabel + next-
// layer count/fill via LDS. Coefficient-free meta: relabel loop writes meta8
// directly with ONE LDS atomic (slot+count combined); no second fill pass,
// no barrier between count and fill. L==2 also emits the final output.
// ---------------------------------------------------------------------------

__global__ __launch_bounds__(1024) void topk_mega_kernel(
    const float* __restrict__ score, const float* __restrict__ p,
    const float* __restrict__ h, float* __restrict__ xo,
    const int* __restrict__ in_r, const int* __restrict__ in_c,
    int* __restrict__ out_r, int* __restrict__ out_c,
    int* __restrict__ meta8, int* __restrict__ srcext,
    int* __restrict__ cnt, float* __restrict__ acc,
    float* __restrict__ outf, int P, int K, int L) {
  __shared__ float sv[1024];
  __shared__ int si[1024];
  __shared__ int snew[1024];
  __shared__ int scnt[512];
  __shared__ float s_pn;
  __shared__ float4 smx[32][32], ssm[32][32];
  int g = blockIdx.x;
  int t = threadIdx.x;

  if (L < 2 && t < 512) scnt[t] = 0;
  snew[t] = -1;
  if (t < 128) { float v = p[t]; sv[t] = v * v; }
  __syncthreads();
  for (int off = 64; off; off >>= 1) {
    if (t < off) sv[t] += sv[t + off];
    __syncthreads();
  }
  if (t == 0) s_pn = sqrtf(sv[0]);
  __syncthreads();
  float pn = s_pn;

  sv[t] = score[(size_t)g * P + t];
  si[t] = t;
  for (int size = 2; size <= P; size <<= 1) {
    for (int stride = size >> 1; stride; stride >>= 1) {
      __syncthreads();
      int j = t ^ stride;
      if (j > t) {
        float a = sv[t], b = sv[j];
        int ia = si[t], ib = si[j];
        bool tFirst = (a > b) || (a == b && ia < ib);
        bool up = ((t & size) == 0);
        if (up ? !tFirst : tFirst) {
          sv[t] = b; sv[j] = a;
          si[t] = ib; si[j] = ia;
        }
      }
    }
  }
  __syncthreads();
  if (t < K) {
    snew[si[t]] = t;                           // graph-LOCAL new id
    sv[t] = tanhf(sv[t] / pn);                 // sv now holds the scale
  }
  __syncthreads();

  // ---- gather + readout: group = 32 lanes, 16 rows per group ----
  int lane = t & 31, grp = t >> 5;             // ngrp = P/32; K/ngrp == 16
  const float4* h4 = (const float4*)h;
  float4* xo4 = (float4*)xo;
  size_t hbase = (size_t)g * P * 32;
  float4 mx = make_float4(-INFINITY, -INFINITY, -INFINITY, -INFINITY);
  float4 sm = make_float4(0.f, 0.f, 0.f, 0.f);
  #pragma unroll
  for (int i = 0; i < 16; ++i) {
    int j = grp * 16 + i;
    float th = sv[j];
    float4 v = h4[hbase + (size_t)si[j] * 32 + lane];
    v.x *= th; v.y *= th; v.z *= th; v.w *= th;
    xo4[((size_t)g * K + j) * 32 + lane] = v;
    mx.x = fmaxf(mx.x, v.x); mx.y = fmaxf(mx.y, v.y);
    mx.z = fmaxf(mx.z, v.z); mx.w = fmaxf(mx.w, v.w);
    sm.x += v.x; sm.y += v.y; sm.z += v.z; sm.w += v.w;
  }
  smx[grp][lane] = mx;
  ssm[grp][lane] = sm;
  __syncthreads();
  int ngrp = P >> 5;
  if (grp == 0) {
    for (int s2 = 1; s2 < ngrp; ++s2) {
      float4 m2 = smx[s2][lane], s3 = ssm[s2][lane];
      mx.x = fmaxf(mx.x, m2.x); mx.y = fmaxf(mx.y, m2.y);
      mx.z = fmaxf(mx.z, m2.z); mx.w = fmaxf(mx.w, m2.w);
      sm.x += s3.x; sm.y += s3.y; sm.z += s3.z; sm.w += s3.w;
    }
    int c0 = lane * 4;
    if (L < 2) {
      float* amax = acc + (size_t)L * BG * 256 + (size_t)g * 256;
      float* asum = amax + 128;
      amax[c0 + 0] = mx.x; amax[c0 + 1] = mx.y;
      amax[c0 + 2] = mx.z; amax[c0 + 3] = mx.w;
      asum[c0 + 0] = sm.x; asum[c0 + 1] = sm.y;
      asum[c0 + 2] = sm.z; asum[c0 + 3] = sm.w;
    } else {                                   // stash own readout in sv
      sv[c0 + 0] = mx.x; sv[c0 + 1] = mx.y;
      sv[c0 + 2] = mx.z; sv[c0 + 3] = mx.w;
      sv[128 + c0 + 0] = sm.x; sv[128 + c0 + 1] = sm.y;
      sv[128 + c0 + 2] = sm.z; sv[128 + c0 + 3] = sm.w;
    }
  }

  if (L == 2) {                                // fold final combine in
    __syncthreads();
    float v;
    const float* a0 = acc + (size_t)g * 256;
    const float* a1 = acc + (size_t)BG * 256 + (size_t)g * 256;
    if (t < 128) {
      v = a0[t] + a1[t] + sv[t];
    } else {
      v = a0[t] * (1.f / 512.f) + a1[t] * (1.f / 256.f) + sv[t] * (1.f / 128.f);
    }
    outf[g * 256 + t] = v;
    return;
  }

  // ---- relabel + count + fill in ONE pass (single LDS atomic per edge) ----
  int ept = EPG / P;                           // 8 (P=1024) or 16 (P=512)
  int ebase = g * EPG;
  for (int i = 0; i < ept; ++i) {
    int e = ebase + i * P + t;                 // coalesced
    int r = in_r[e];
    int nr = -1, nc = -1;
    if (r >= 0) {
      nr = snew[r & (P - 1)];
      nc = snew[in_c[e] & (P - 1)];
    }
    bool ok = (nr >= 0) && (nc >= 0);
    out_r[e] = ok ? g * K + nr : -1;
    out_c[e] = ok ? g * K + nc : -1;
    if (ok) {
      int pos = atomicAdd(&scnt[nc], 1);
      size_t gnode = (size_t)g * K + nc;
      if (pos < PRE) {
        meta8[gnode * PRE + pos] = nr;
      } else if (pos < CAP) {
        srcext[gnode * CAP + pos] = nr;
      }
    }
  }
  __syncthreads();                             // scnt complete
  if (t < K) cnt[g * K + t] = scnt[t];         // deg for next agg (coalesced)
}

// ---------------------------------------------------------------------------
// launch
// ---------------------------------------------------------------------------

extern "C" void kernel_launch(void* const* d_in, const int* in_sizes, int n_in,
                              void* d_out, int out_size, void* d_ws, size_t ws_size,
                              hipStream_t stream) {
  const float* x0 = (const float*)d_in[0];
  const int* erow = (const int*)d_in[1];
  const int* ecol = (const int*)d_in[2];
  const float* Wm[3] = {(const float*)d_in[3], (const float*)d_in[6], (const float*)d_in[9]};
  const float* bm[3] = {(const float*)d_in[4], (const float*)d_in[7], (const float*)d_in[10]};
  const float* pm[3] = {(const float*)d_in[5], (const float*)d_in[8], (const float*)d_in[11]};

  char* w = (char*)d_ws;
  size_t off = 0;
  auto alloc = [&](size_t bytes) -> void* {
    void* ptr = w + off;
    off = (off + bytes + 255) & ~(size_t)255;
    return ptr;
  };
  int* cur_row = (int*)alloc((size_t)NEDGE * 4);
  int* cur_col = (int*)alloc((size_t)NEDGE * 4);
  int* meta8   = (int*)alloc((size_t)NMAX * PRE * 4);
  int* srcext  = (int*)alloc((size_t)NMAX * CAP * 4);
  int* cnt     = (int*)alloc((size_t)NMAX * 4);
  float* score = (float*)alloc((size_t)NMAX * 4);
  float* acc   = (float*)alloc((size_t)2 * BG * 256 * 4);
  float* zh    = (float*)alloc((size_t)NMAX * HDIM * 4);
  float* x1    = (float*)alloc((size_t)BG * 512 * HDIM * 4);
  float* x2    = (float*)alloc((size_t)BG * 256 * HDIM * 4);
  float* x3    = (float*)alloc((size_t)BG * 128 * HDIM * 4);
  ushort* wpk  = (ushort*)alloc((size_t)3 * 3 * 16384 * 2);  // packed W splits

  // allow >64 KB dynamic LDS for the agg kernel (L0 needs 132 KB)
  hipFuncSetAttribute((const void*)agg_lds_kernel,
                      hipFuncAttributeMaxDynamicSharedMemorySize, 152 * 1024);

  hipMemsetAsync(cnt, 0, (size_t)NMAX * 4, stream);
  countfill_kernel<<<NEDGE / 256, 256, 0, stream>>>(erow, ecol, cnt, meta8,
                                                    srcext, NPER - 1);
  wsplit_kernel<<<(3 * 16384) / 256, 256, 0, stream>>>(Wm[0], Wm[1], Wm[2], wpk);

  const float* xin = x0;
  float* xout[3] = {x1, x2, x3};
  int Ps[3] = {1024, 512, 256};

  for (int L = 0; L < 3; ++L) {
    int P = Ps[L];
    int K = P >> 1;
    int n = BG * P;
    const int* in_r = (L == 0) ? erow : cur_row;
    const int* in_c = (L == 0) ? ecol : cur_col;
    size_t ldsBytes = (size_t)(P * 33) * 4;    // 32-ch chunk + dinv

    agg_lds_kernel<<<BG * 4, 1024, ldsBytes, stream>>>(
        xin, zh, meta8, srcext, cnt, P);
    conv_mfma_kernel<<<n / CROWS, 256, 0, stream>>>(
        zh, wpk + (size_t)L * 3 * 16384, bm[L], pm[L], score);
    topk_mega_kernel<<<BG, P, 0, stream>>>(
        score, pm[L], zh, xout[L], in_r, in_c, cur_row, cur_col,
        meta8, srcext, cnt, acc, (float*)d_out, P, K, L);
    xin = xout[L];
  }
}

// Round 7
// 373.028 us; speedup vs baseline: 1.3114x; 1.0240x over previous
//
#include <hip/hip_runtime.h>
#include <math.h>

#define BG   128            // graphs
#define NPER 1024           // nodes per graph, level 0
#define HDIM 128            // hidden
#define NEDGE (BG * NPER * 8)
#define NMAX (BG * NPER)    // 131072
#define EPG  (NEDGE / BG)   // 8192 edges per graph (contiguous slice!)
#define CAP  48             // per-node edge capacity (Poisson(8) tail ~1e-15)
#define PRE  16             // packed-meta entries per node (P(deg>16) ~ 0.4%)
#define CROWS 64            // conv tile rows

typedef __attribute__((ext_vector_type(8))) short s16x8;   // 8 bf16 (4 VGPRs)
typedef __attribute__((ext_vector_type(4))) float f32x4;   // MFMA C/D

static __device__ __forceinline__ ushort f2bf(float f) {   // RNE f32 -> bf16
  uint u = __float_as_uint(f);
  return (ushort)((u + 0x7fffu + ((u >> 16) & 1u)) >> 16);
}
static __device__ __forceinline__ float bf2f(ushort h) {
  return __uint_as_float(((uint)h) << 16);
}

// ---------------------------------------------------------------------------
// L0 merged count+fill: ONE atomic per edge gives both the slot position and
// (at the end) the degree. meta holds ONLY graph-local src ids.
// ---------------------------------------------------------------------------

__global__ __launch_bounds__(256) void countfill_kernel(
    const int* __restrict__ cr, const int* __restrict__ cc,
    int* __restrict__ cnt, int* __restrict__ meta8,
    int* __restrict__ srcext, int mask) {
  int e = blockIdx.x * 256 + threadIdx.x;
  int c = cc[e];
  int rl = cr[e] & mask;                       // graph-local row index
  int pos = atomicAdd(&cnt[c], 1);
  if (pos < PRE) {
    meta8[(size_t)c * PRE + pos] = rl;
  } else if (pos < CAP) {
    srcext[(size_t)c * CAP + pos] = rl;
  }
}

extern __shared__ float ldsbuf[];

// ---------------------------------------------------------------------------
// LDS-resident aggregation R7 = R6 + false-dependency fix (only change).
// R6 kept 44 VGPRs: the compiler reused edge4's 4 temporaries across
// batches -> batch k+1's ds_reads stalled on batch k's fmas (4 serial LDS
// round-trips per node). Now: 16 edge reads in DISTINCT named float4s, two
// 8-deep clusters (~105 VGPR, stays at 4 waves/SIMD). Masks eliminated:
// invalid slots read the dst's own row (valid ids need no sanitize) and the
// epilogue subtracts the over-count once: o = (sum - (PRE-dp)*w) * dc.
// ---------------------------------------------------------------------------

__global__ __launch_bounds__(1024) void agg_lds_kernel(
    const float* __restrict__ x, float* __restrict__ z,
    const int* __restrict__ meta8, const int* __restrict__ srcext,
    const int* __restrict__ deg, int npg) {
  float* sX = ldsbuf;                          // [npg][32], pre-scaled
  float* sDinv = sX + npg * 32;                // [npg]
  int g = blockIdx.x >> 2;
  int chunk = blockIdx.x & 3;
  int t = threadIdx.x;
  int base = g * npg;

  const float4* x4 = (const float4*)x;
  float4* sX4 = (float4*)sX;
  for (int i = t; i < npg * 8; i += 1024) {
    int r = i >> 3, l8 = i & 7;
    float dv = rsqrtf((float)deg[base + r] + 1.0f);
    float4 v = x4[(size_t)(base + r) * 32 + chunk * 8 + l8];
    v.x *= dv; v.y *= dv; v.z *= dv; v.w *= dv;
    sX4[i] = v;
  }
  for (int i = t; i < npg; i += 1024)
    sDinv[i] = rsqrtf((float)deg[base + i] + 1.0f);
  __syncthreads();

  int dl = t >> 3, l = t & 7;                  // dst-local slot, lane 0..7
  const int4* m4 = (const int4*)meta8;
  float4* z4 = (float4*)z;

  for (int dst = dl; dst < npg; dst += 128) {
    int node = base + dst;
    int4 i0 = m4[(size_t)node * 4 + 0];        // 16 ids, group-uniform addr
    int4 i1 = m4[(size_t)node * 4 + 1];        // (L1 broadcast), vmcnt
    int4 i2 = m4[(size_t)node * 4 + 2];
    int4 i3 = m4[(size_t)node * 4 + 3];
    int dg = deg[node];
    int d = dg > CAP ? CAP : dg;
    int dp = d > PRE ? PRE : d;
    float dc = sDinv[dst];

    // ---- cluster A: self + edges 0..7, 9 independent ds_read_b128 ----
    int sA0 = (0 < dp) ? i0.x : dst;           // invalid -> own row (valid
    int sA1 = (1 < dp) ? i0.y : dst;           //  ids are in-range: no mask)
    int sA2 = (2 < dp) ? i0.z : dst;
    int sA3 = (3 < dp) ? i0.w : dst;
    int sA4 = (4 < dp) ? i1.x : dst;
    int sA5 = (5 < dp) ? i1.y : dst;
    int sA6 = (6 < dp) ? i1.z : dst;
    int sA7 = (7 < dp) ? i1.w : dst;
    float4 w  = sX4[dst * 8 + l];              // self row (kept for corr)
    float4 p0 = sX4[sA0 * 8 + l];
    float4 p1 = sX4[sA1 * 8 + l];
    float4 p2 = sX4[sA2 * 8 + l];
    float4 p3 = sX4[sA3 * 8 + l];
    float4 p4 = sX4[sA4 * 8 + l];
    float4 p5 = sX4[sA5 * 8 + l];
    float4 p6 = sX4[sA6 * 8 + l];
    float4 p7 = sX4[sA7 * 8 + l];
    float4 a0, a1, a2, a3;
    a0.x = w.x + p0.x; a0.y = w.y + p0.y; a0.z = w.z + p0.z; a0.w = w.w + p0.w;
    a1.x = p1.x + p5.x; a1.y = p1.y + p5.y; a1.z = p1.z + p5.z; a1.w = p1.w + p5.w;
    a2.x = p2.x + p6.x; a2.y = p2.y + p6.y; a2.z = p2.z + p6.z; a2.w = p2.w + p6.w;
    a3.x = p3.x + p7.x; a3.y = p3.y + p7.y; a3.z = p3.z + p7.z; a3.w = p3.w + p7.w;
    a0.x += p4.x; a0.y += p4.y; a0.z += p4.z; a0.w += p4.w;

    // ---- cluster B: edges 8..15, 8 independent ds_read_b128 ----
    int sB0 = (8 < dp) ? i2.x : dst;
    int sB1 = (9 < dp) ? i2.y : dst;
    int sB2 = (10 < dp) ? i2.z : dst;
    int sB3 = (11 < dp) ? i2.w : dst;
    int sB4 = (12 < dp) ? i3.x : dst;
    int sB5 = (13 < dp) ? i3.y : dst;
    int sB6 = (14 < dp) ? i3.z : dst;
    int sB7 = (15 < dp) ? i3.w : dst;
    float4 q0 = sX4[sB0 * 8 + l];
    float4 q1 = sX4[sB1 * 8 + l];
    float4 q2 = sX4[sB2 * 8 + l];
    float4 q3 = sX4[sB3 * 8 + l];
    float4 q4 = sX4[sB4 * 8 + l];
    float4 q5 = sX4[sB5 * 8 + l];
    float4 q6 = sX4[sB6 * 8 + l];
    float4 q7 = sX4[sB7 * 8 + l];
    a0.x += q0.x; a0.y += q0.y; a0.z += q0.z; a0.w += q0.w;
    a1.x += q1.x; a1.y += q1.y; a1.z += q1.z; a1.w += q1.w;
    a2.x += q2.x; a2.y += q2.y; a2.z += q2.z; a2.w += q2.w;
    a3.x += q3.x; a3.y += q3.y; a3.z += q3.z; a3.w += q3.w;
    a0.x += q4.x; a0.y += q4.y; a0.z += q4.z; a0.w += q4.w;
    a1.x += q5.x; a1.y += q5.y; a1.z += q5.z; a1.w += q5.w;
    a2.x += q6.x; a2.y += q6.y; a2.z += q6.z; a2.w += q6.w;
    a3.x += q7.x; a3.y += q7.y; a3.z += q7.z; a3.w += q7.w;

    if (d > PRE) {                             // rare overflow (deg > 16)
      for (int e2 = PRE; e2 < d; ++e2) {
        int rl = srcext[(size_t)node * CAP + e2];
        float4 v0 = sX4[rl * 8 + l];
        a0.x += v0.x; a0.y += v0.y; a0.z += v0.z; a0.w += v0.w;
      }
    }

    float corr = (float)(PRE - dp);            // over-counted self reads
    float4 o;
    o.x = (a0.x + a1.x + a2.x + a3.x - corr * w.x) * dc;
    o.y = (a0.y + a1.y + a2.y + a3.y - corr * w.y) * dc;
    o.z = (a0.z + a1.z + a2.z + a3.z - corr * w.z) * dc;
    o.w = (a0.w + a1.w + a2.w + a3.w - corr * w.w) * dc;
    z4[(size_t)node * 32 + chunk * 8 + l] = o;
  }
}

// ---------------------------------------------------------------------------
// W prep: 3-way bf16 split (hi/mid/lo, residual <= 2^-27 rel) of each level's
// W, packed directly in MFMA B-fragment order for 16x16x32_bf16:
//   B[k][n]: lane l holds k = kt*32 + (l>>4)*8 + i, n = nt*16 + (l&15)
//   layout: [L][split][kt][nt][lane][i]  (each fragment = 16 B contiguous)
// Runs once; 3*3*32 KB total.
// ---------------------------------------------------------------------------

__global__ __launch_bounds__(256) void wsplit_kernel(
    const float* __restrict__ W0, const float* __restrict__ W1,
    const float* __restrict__ W2, ushort* __restrict__ wpk) {
  int id = blockIdx.x * 256 + threadIdx.x;     // 3*16384 total
  int L = id >> 14;
  int r = id & 16383;                          // ((kt*8+nt)*64+lane)*8+i
  int i = r & 7;
  int lane = (r >> 3) & 63;
  int nt = (r >> 9) & 7;
  int kt = (r >> 12) & 3;
  int k = kt * 32 + (lane >> 4) * 8 + i;
  int n = nt * 16 + (lane & 15);
  const float* W = (L == 0) ? W0 : (L == 1) ? W1 : W2;
  float v = W[k * HDIM + n];
  ushort h = f2bf(v);
  float r1 = v - bf2f(h);
  ushort m = f2bf(r1);
  ushort lo = f2bf(r1 - bf2f(m));
  size_t base = (size_t)L * 3 * 16384 + (size_t)r;
  wpk[base] = h;
  wpk[base + 16384] = m;
  wpk[base + 32768] = lo;
}

// ---------------------------------------------------------------------------
// conv via MFMA split-precision: h = relu(z @ W + b) in-place; score = h . p.
// Each wave owns 16 rows (4 waves = 64 rows/block). fp32 z is 3-way bf16
// split in registers; 6 product terms (hh,hm,mh,hl,lh,mm) per K-tile keep
// error ~2^-27 rel (fp32-rounding level -> topk ordering preserved).
// B-fragments: coalesced 16 B/lane dwordx4 from pre-packed wpk (L2-hot).
// No LDS, no barriers. 192 MFMAs/wave; dispatch is memory-bound on z/h.
// ---------------------------------------------------------------------------

__global__ __launch_bounds__(256) void conv_mfma_kernel(
    float* __restrict__ zh, const ushort* __restrict__ wpk,
    const float* __restrict__ bias, const float* __restrict__ p,
    float* __restrict__ score) {
  int t = threadIdx.x;
  int wv = t >> 6, l = t & 63;
  int lr = l & 15, lq = l >> 4;                // A-row in tile, quarter
  int arow = blockIdx.x * CROWS + wv * 16 + lr;
  const float* zrow = zh + (size_t)arow * HDIM + lq * 8;

  // ---- load + 3-way split A fragments (k = kt*32 + lq*8 + i) ----
  s16x8 ah[4], am[4], al[4];
  #pragma unroll
  for (int kt = 0; kt < 4; ++kt) {
    float4 v0 = ((const float4*)(zrow + kt * 32))[0];
    float4 v1 = ((const float4*)(zrow + kt * 32))[1];
    float f[8] = {v0.x, v0.y, v0.z, v0.w, v1.x, v1.y, v1.z, v1.w};
    #pragma unroll
    for (int i = 0; i < 8; ++i) {
      ushort h = f2bf(f[i]);
      float r1 = f[i] - bf2f(h);
      ushort m = f2bf(r1);
      ushort lo = f2bf(r1 - bf2f(m));
      ah[kt][i] = (short)h; am[kt][i] = (short)m; al[kt][i] = (short)lo;
    }
  }

  f32x4 acc[8];
  #pragma unroll
  for (int nt = 0; nt < 8; ++nt) acc[nt] = (f32x4)(0.f);

  const s16x8* wh = (const s16x8*)wpk;         // fragment-granular views
  const s16x8* wm = wh + 2048;
  const s16x8* wl = wm + 2048;

  #pragma unroll
  for (int kt = 0; kt < 4; ++kt) {
    #pragma unroll
    for (int nt = 0; nt < 8; ++nt) {
      int fi = (kt * 8 + nt) * 64 + l;
      s16x8 bh = wh[fi];
      s16x8 bm = wm[fi];
      s16x8 bl = wl[fi];
      acc[nt] = __builtin_amdgcn_mfma_f32_16x16x32_bf16(ah[kt], bh, acc[nt], 0, 0, 0);
      acc[nt] = __builtin_amdgcn_mfma_f32_16x16x32_bf16(ah[kt], bm, acc[nt], 0, 0, 0);
      acc[nt] = __builtin_amdgcn_mfma_f32_16x16x32_bf16(am[kt], bh, acc[nt], 0, 0, 0);
      acc[nt] = __builtin_amdgcn_mfma_f32_16x16x32_bf16(ah[kt], bl, acc[nt], 0, 0, 0);
      acc[nt] = __builtin_amdgcn_mfma_f32_16x16x32_bf16(al[kt], bh, acc[nt], 0, 0, 0);
      acc[nt] = __builtin_amdgcn_mfma_f32_16x16x32_bf16(am[kt], bm, acc[nt], 0, 0, 0);
    }
  }

  // ---- epilogue: bias + relu + score + in-place store ----
  // C/D layout (m89-verified): row = lq*4 + j, col = nt*16 + lr
  int orow = blockIdx.x * CROWS + wv * 16 + lq * 4;
  float part[4] = {0.f, 0.f, 0.f, 0.f};
  #pragma unroll
  for (int nt = 0; nt < 8; ++nt) {
    float bv = bias[nt * 16 + lr];
    float pv = p[nt * 16 + lr];
    #pragma unroll
    for (int j = 0; j < 4; ++j) {
      float hv = fmaxf(acc[nt][j] + bv, 0.f);
      part[j] += hv * pv;
      zh[(size_t)(orow + j) * HDIM + nt * 16 + lr] = hv;
    }
  }
  #pragma unroll
  for (int j = 0; j < 4; ++j) {
    #pragma unroll
    for (int s = 1; s < 16; s <<= 1) part[j] += __shfl_xor(part[j], s);
    if (lr == 0) score[orow + j] = part[j];
  }
}

// ---------------------------------------------------------------------------
// MEGA: per-graph block (P threads) — sort + pool/readout + relabel + next-
// layer count/fill via LDS. Coefficient-free meta: relabel loop writes meta8
// directly with ONE LDS atomic (slot+count combined); no second fill pass,
// no barrier between count and fill. L==2 also emits the final output.
// ---------------------------------------------------------------------------

__global__ __launch_bounds__(1024) void topk_mega_kernel(
    const float* __restrict__ score, const float* __restrict__ p,
    const float* __restrict__ h, float* __restrict__ xo,
    const int* __restrict__ in_r, const int* __restrict__ in_c,
    int* __restrict__ out_r, int* __restrict__ out_c,
    int* __restrict__ meta8, int* __restrict__ srcext,
    int* __restrict__ cnt, float* __restrict__ acc,
    float* __restrict__ outf, int P, int K, int L) {
  __shared__ float sv[1024];
  __shared__ int si[1024];
  __shared__ int snew[1024];
  __shared__ int scnt[512];
  __shared__ float s_pn;
  __shared__ float4 smx[32][32], ssm[32][32];
  int g = blockIdx.x;
  int t = threadIdx.x;

  if (L < 2 && t < 512) scnt[t] = 0;
  snew[t] = -1;
  if (t < 128) { float v = p[t]; sv[t] = v * v; }
  __syncthreads();
  for (int off = 64; off; off >>= 1) {
    if (t < off) sv[t] += sv[t + off];
    __syncthreads();
  }
  if (t == 0) s_pn = sqrtf(sv[0]);
  __syncthreads();
  float pn = s_pn;

  sv[t] = score[(size_t)g * P + t];
  si[t] = t;
  for (int size = 2; size <= P; size <<= 1) {
    for (int stride = size >> 1; stride; stride >>= 1) {
      __syncthreads();
      int j = t ^ stride;
      if (j > t) {
        float a = sv[t], b = sv[j];
        int ia = si[t], ib = si[j];
        bool tFirst = (a > b) || (a == b && ia < ib);
        bool up = ((t & size) == 0);
        if (up ? !tFirst : tFirst) {
          sv[t] = b; sv[j] = a;
          si[t] = ib; si[j] = ia;
        }
      }
    }
  }
  __syncthreads();
  if (t < K) {
    snew[si[t]] = t;                           // graph-LOCAL new id
    sv[t] = tanhf(sv[t] / pn);                 // sv now holds the scale
  }
  __syncthreads();

  // ---- gather + readout: group = 32 lanes, 16 rows per group ----
  int lane = t & 31, grp = t >> 5;             // ngrp = P/32; K/ngrp == 16
  const float4* h4 = (const float4*)h;
  float4* xo4 = (float4*)xo;
  size_t hbase = (size_t)g * P * 32;
  float4 mx = make_float4(-INFINITY, -INFINITY, -INFINITY, -INFINITY);
  float4 sm = make_float4(0.f, 0.f, 0.f, 0.f);
  #pragma unroll
  for (int i = 0; i < 16; ++i) {
    int j = grp * 16 + i;
    float th = sv[j];
    float4 v = h4[hbase + (size_t)si[j] * 32 + lane];
    v.x *= th; v.y *= th; v.z *= th; v.w *= th;
    xo4[((size_t)g * K + j) * 32 + lane] = v;
    mx.x = fmaxf(mx.x, v.x); mx.y = fmaxf(mx.y, v.y);
    mx.z = fmaxf(mx.z, v.z); mx.w = fmaxf(mx.w, v.w);
    sm.x += v.x; sm.y += v.y; sm.z += v.z; sm.w += v.w;
  }
  smx[grp][lane] = mx;
  ssm[grp][lane] = sm;
  __syncthreads();
  int ngrp = P >> 5;
  if (grp == 0) {
    for (int s2 = 1; s2 < ngrp; ++s2) {
      float4 m2 = smx[s2][lane], s3 = ssm[s2][lane];
      mx.x = fmaxf(mx.x, m2.x); mx.y = fmaxf(mx.y, m2.y);
      mx.z = fmaxf(mx.z, m2.z); mx.w = fmaxf(mx.w, m2.w);
      sm.x += s3.x; sm.y += s3.y; sm.z += s3.z; sm.w += s3.w;
    }
    int c0 = lane * 4;
    if (L < 2) {
      float* amax = acc + (size_t)L * BG * 256 + (size_t)g * 256;
      float* asum = amax + 128;
      amax[c0 + 0] = mx.x; amax[c0 + 1] = mx.y;
      amax[c0 + 2] = mx.z; amax[c0 + 3] = mx.w;
      asum[c0 + 0] = sm.x; asum[c0 + 1] = sm.y;
      asum[c0 + 2] = sm.z; asum[c0 + 3] = sm.w;
    } else {                                   // stash own readout in sv
      sv[c0 + 0] = mx.x; sv[c0 + 1] = mx.y;
      sv[c0 + 2] = mx.z; sv[c0 + 3] = mx.w;
      sv[128 + c0 + 0] = sm.x; sv[128 + c0 + 1] = sm.y;
      sv[128 + c0 + 2] = sm.z; sv[128 + c0 + 3] = sm.w;
    }
  }

  if (L == 2) {                                // fold final combine in
    __syncthreads();
    float v;
    const float* a0 = acc + (size_t)g * 256;
    const float* a1 = acc + (size_t)BG * 256 + (size_t)g * 256;
    if (t < 128) {
      v = a0[t] + a1[t] + sv[t];
    } else {
      v = a0[t] * (1.f / 512.f) + a1[t] * (1.f / 256.f) + sv[t] * (1.f / 128.f);
    }
    outf[g * 256 + t] = v;
    return;
  }

  // ---- relabel + count + fill in ONE pass (single LDS atomic per edge) ----
  int ept = EPG / P;                           // 8 (P=1024) or 16 (P=512)
  int ebase = g * EPG;
  for (int i = 0; i < ept; ++i) {
    int e = ebase + i * P + t;                 // coalesced
    int r = in_r[e];
    int nr = -1, nc = -1;
    if (r >= 0) {
      nr = snew[r & (P - 1)];
      nc = snew[in_c[e] & (P - 1)];
    }
    bool ok = (nr >= 0) && (nc >= 0);
    out_r[e] = ok ? g * K + nr : -1;
    out_c[e] = ok ? g * K + nc : -1;
    if (ok) {
      int pos = atomicAdd(&scnt[nc], 1);
      size_t gnode = (size_t)g * K + nc;
      if (pos < PRE) {
        meta8[gnode * PRE + pos] = nr;
      } else if (pos < CAP) {
        srcext[gnode * CAP + pos] = nr;
      }
    }
  }
  __syncthreads();                             // scnt complete
  if (t < K) cnt[g * K + t] = scnt[t];         // deg for next agg (coalesced)
}

// ---------------------------------------------------------------------------
// launch
// ---------------------------------------------------------------------------

extern "C" void kernel_launch(void* const* d_in, const int* in_sizes, int n_in,
                              void* d_out, int out_size, void* d_ws, size_t ws_size,
                              hipStream_t stream) {
  const float* x0 = (const float*)d_in[0];
  const int* erow = (const int*)d_in[1];
  const int* ecol = (const int*)d_in[2];
  const float* Wm[3] = {(const float*)d_in[3], (const float*)d_in[6], (const float*)d_in[9]};
  const float* bm[3] = {(const float*)d_in[4], (const float*)d_in[7], (const float*)d_in[10]};
  const float* pm[3] = {(const float*)d_in[5], (const float*)d_in[8], (const float*)d_in[11]};

  char* w = (char*)d_ws;
  size_t off = 0;
  auto alloc = [&](size_t bytes) -> void* {
    void* ptr = w + off;
    off = (off + bytes + 255) & ~(size_t)255;
    return ptr;
  };
  int* cur_row = (int*)alloc((size_t)NEDGE * 4);
  int* cur_col = (int*)alloc((size_t)NEDGE * 4);
  int* meta8   = (int*)alloc((size_t)NMAX * PRE * 4);
  int* srcext  = (int*)alloc((size_t)NMAX * CAP * 4);
  int* cnt     = (int*)alloc((size_t)NMAX * 4);
  float* score = (float*)alloc((size_t)NMAX * 4);
  float* acc   = (float*)alloc((size_t)2 * BG * 256 * 4);
  float* zh    = (float*)alloc((size_t)NMAX * HDIM * 4);
  float* x1    = (float*)alloc((size_t)BG * 512 * HDIM * 4);
  float* x2    = (float*)alloc((size_t)BG * 256 * HDIM * 4);
  float* x3    = (float*)alloc((size_t)BG * 128 * HDIM * 4);
  ushort* wpk  = (ushort*)alloc((size_t)3 * 3 * 16384 * 2);  // packed W splits

  // allow >64 KB dynamic LDS for the agg kernel (L0 needs 132 KB)
  hipFuncSetAttribute((const void*)agg_lds_kernel,
                      hipFuncAttributeMaxDynamicSharedMemorySize, 152 * 1024);

  hipMemsetAsync(cnt, 0, (size_t)NMAX * 4, stream);
  countfill_kernel<<<NEDGE / 256, 256, 0, stream>>>(erow, ecol, cnt, meta8,
                                                    srcext, NPER - 1);
  wsplit_kernel<<<(3 * 16384) / 256, 256, 0, stream>>>(Wm[0], Wm[1], Wm[2], wpk);

  const float* xin = x0;
  float* xout[3] = {x1, x2, x3};
  int Ps[3] = {1024, 512, 256};

  for (int L = 0; L < 3; ++L) {
    int P = Ps[L];
    int K = P >> 1;
    int n = BG * P;
    const int* in_r = (L == 0) ? erow : cur_row;
    const int* in_c = (L == 0) ? ecol : cur_col;
    size_t ldsBytes = (size_t)(P * 33) * 4;    // 32-ch chunk + dinv

    agg_lds_kernel<<<BG * 4, 1024, ldsBytes, stream>>>(
        xin, zh, meta8, srcext, cnt, P);
    conv_mfma_kernel<<<n / CROWS, 256, 0, stream>>>(
        zh, wpk + (size_t)L * 3 * 16384, bm[L], pm[L], score);
    topk_mega_kernel<<<BG, P, 0, stream>>>(
        score, pm[L], zh, xout[L], in_r, in_c, cur_row, cur_col,
        meta8, srcext, cnt, acc, (float*)d_out, P, K, L);
    xin = xout[L];
  }
}